// Round 7
// baseline (4285.295 us; speedup 1.0000x reference)
//
#include <hip/hip_runtime.h>
#include <hip/hip_bf16.h>
#include <stdint.h>

// GRU fused scan: B=128, T=512, I=H=512.
// 256 wgs x 192 threads (3 waves = gates r,z,n). wg (bgrp=id&7, ugrp=id>>3)
// owns batch rows [bgrp*16,+16) and hidden units [ugrp*16,+16).
// Weights live in registers/AGPRs as bf16 MFMA fragments. h double-buffered in
// d_ws (bf16). Sync per (step,wg): one monotonic flag word (flag[wg]=t+1).
// Runtime XCD verdict (HW_REG_XCC_ID, one-time, 1 KB xcdmap in d_ws): if all
// 32 wgs of a bgrp share an XCD, that bgrp's h/flag exchange runs at L2 scope
// (plain stores acked by vmcnt(0), sc0 loads bypassing L1); otherwise the
// proven agent-scope (IF-point) path from round 6 is used, bit-identical
// arithmetic either way. ws footprint 258 KB total (<= proven 272 KB).
// f32->bf16 conversion via v_cvt_pk_bf16_f32 (1 VALU op / 2 floats).

static constexpr int INPUT = 512;
static constexpr int HID   = 512;
static constexpr int NB    = 128;
static constexpr int TLEN  = 512;
static constexpr int BGRPS = 8;
static constexpr int UGRPS = 32;

typedef __attribute__((ext_vector_type(4))) float f32x4;
typedef __attribute__((ext_vector_type(8))) short s16x8;
typedef __attribute__((ext_vector_type(4))) int   i32x4;

static __device__ __forceinline__ unsigned short f2bf(float f) {
  unsigned u = __builtin_bit_cast(unsigned, f);
  u += 0x7FFFu + ((u >> 16) & 1u);   // RNE
  return (unsigned short)(u >> 16);
}

// 8 consecutive fp32 -> bf16x8 via packed-convert (RNE), 4 VALU ops total
static __device__ __forceinline__ s16x8 cvt8(const float* p) {
  f32x4 a = *(const f32x4*)p;
  f32x4 b = *(const f32x4*)(p + 4);
  unsigned r0, r1, r2, r3;
  asm("v_cvt_pk_bf16_f32 %0, %1, %2" : "=v"(r0) : "v"(a[0]), "v"(a[1]));
  asm("v_cvt_pk_bf16_f32 %0, %1, %2" : "=v"(r1) : "v"(a[2]), "v"(a[3]));
  asm("v_cvt_pk_bf16_f32 %0, %1, %2" : "=v"(r2) : "v"(b[0]), "v"(b[1]));
  asm("v_cvt_pk_bf16_f32 %0, %1, %2" : "=v"(r3) : "v"(b[2]), "v"(b[3]));
  union { unsigned u[4]; s16x8 s; } r;
  r.u[0] = r0; r.u[1] = r1; r.u[2] = r2; r.u[3] = r3;
  return r.s;
}

__global__ __launch_bounds__(192, 2) void gru_fused(
    const float* __restrict__ xs, const float* __restrict__ wih,
    const float* __restrict__ whh, const float* __restrict__ bias,
    const float* __restrict__ bias_n, float* __restrict__ out,
    unsigned short* __restrict__ hbuf, unsigned int* __restrict__ flags,
    unsigned int* __restrict__ xcdmap)
{
  const int wg   = blockIdx.x;
  const int bgrp = wg & 7;
  const int ugrp = wg >> 3;
  const int b0   = bgrp * 16;
  const int u0   = ugrp * 16;
  const int tid  = threadIdx.x;
  const int g    = tid >> 6;      // 0=r, 1=z, 2=n
  const int lane = tid & 63;
  const int ln   = lane & 15;     // unit / batch-row index within tile
  const int kg   = lane >> 4;     // k-octet group 0..3

  // ---- publish my physical XCD (one-time, IF scope) ----
  if (tid == 0) {
    unsigned x;
    asm volatile("s_getreg_b32 %0, hwreg(HW_REG_XCC_ID)" : "=s"(x));
    __hip_atomic_store(&xcdmap[wg], x | 0x100u, __ATOMIC_RELAXED, __HIP_MEMORY_SCOPE_AGENT);
  }

  // ---- preload weight fragments (overlaps xcdmap propagation) ----
  const int rowW = g * HID + u0 + ln;      // row of [1536][512] weight matrices
  s16x8 wa[16], wb[16];
#pragma unroll
  for (int ks = 0; ks < 16; ++ks) {
    const int k = ks * 32 + kg * 8;
    wa[ks] = cvt8(wih + (size_t)rowW * INPUT + k);
    wb[ks] = cvt8(whh + (size_t)rowW * HID + k);
  }
  const float bv = bias[rowW];
  const float bn = bias_n[u0 + ln];

  // ---- XCD-locality verdict (uniform & deterministic per bgrp) ----
  __shared__ int fast_sh;
  __shared__ float xch[2][4][16][16];   // dbuf [slot r/z/nx/nh][unit][batch]
  if (tid < 32) {
    unsigned v;
    do {
      v = __hip_atomic_load(&xcdmap[bgrp + 8 * tid], __ATOMIC_RELAXED, __HIP_MEMORY_SCOPE_AGENT);
    } while (v == 0);
    unsigned v0 = (unsigned)__shfl((int)v, 0);
    unsigned long long bal = __ballot(v == v0);
    if (tid == 0) fast_sh = ((bal & 0xFFFFFFFFull) == 0xFFFFFFFFull) ? 1 : 0;
  }
  __syncthreads();
  const bool fast = (fast_sh != 0);

  const float* xrow = xs + (size_t)(b0 + ln) * TLEN * INPUT + kg * 8;
  const int hoff = (b0 + ln) * HID + kg * 8;   // ushort offset within one h slot

  float hold[4] = {0.f, 0.f, 0.f, 0.f};

  // ---- prologue: input-side GEMM for t = 0 ----
  f32x4 acc_a = {bv, bv, bv, bv};
#pragma unroll
  for (int ks = 0; ks < 16; ++ks) {
    s16x8 xa = cvt8(xrow + ks * 32);
    acc_a = __builtin_amdgcn_mfma_f32_16x16x32_bf16(xa, wa[ks], acc_a, 0, 0, 0);
  }

  for (int t = 0; t < TLEN; ++t) {
    // ---- wait: all 32 wgs of my bgrp have published h[t] (flag >= t) ----
    if (t > 0) {
      const unsigned* fp = &flags[bgrp * UGRPS + (lane & 31)];
      unsigned fv;
      if (fast) {
        do {
          asm volatile("global_load_dword %0, %1, off sc0\n\t"
                       "s_waitcnt vmcnt(0)"
                       : "=&v"(fv) : "v"(fp) : "memory");
        } while (~__ballot(fv >= (unsigned)t));
      } else {
        do {
          fv = __hip_atomic_load(fp, __ATOMIC_RELAXED, __HIP_MEMORY_SCOPE_AGENT);
        } while (~__ballot(fv >= (unsigned)t));
      }
      __builtin_amdgcn_sched_barrier(0);   // no hoist of h loads above the wait
    }

    // ---- load h[t] fragments ----
    s16x8 hu[16];
    if (fast) {
      const char* hb = (const char*)(hbuf + (size_t)(t & 1) * (NB * HID) + hoff);
      i32x4 h0,h1,h2,h3,h4,h5,h6,h7,h8,h9,h10,h11,h12,h13,h14,h15;
      asm volatile(
        "global_load_dwordx4 %0,  %16, off sc0\n\t"
        "global_load_dwordx4 %1,  %16, off offset:64 sc0\n\t"
        "global_load_dwordx4 %2,  %16, off offset:128 sc0\n\t"
        "global_load_dwordx4 %3,  %16, off offset:192 sc0\n\t"
        "global_load_dwordx4 %4,  %16, off offset:256 sc0\n\t"
        "global_load_dwordx4 %5,  %16, off offset:320 sc0\n\t"
        "global_load_dwordx4 %6,  %16, off offset:384 sc0\n\t"
        "global_load_dwordx4 %7,  %16, off offset:448 sc0\n\t"
        "global_load_dwordx4 %8,  %16, off offset:512 sc0\n\t"
        "global_load_dwordx4 %9,  %16, off offset:576 sc0\n\t"
        "global_load_dwordx4 %10, %16, off offset:640 sc0\n\t"
        "global_load_dwordx4 %11, %16, off offset:704 sc0\n\t"
        "global_load_dwordx4 %12, %16, off offset:768 sc0\n\t"
        "global_load_dwordx4 %13, %16, off offset:832 sc0\n\t"
        "global_load_dwordx4 %14, %16, off offset:896 sc0\n\t"
        "global_load_dwordx4 %15, %16, off offset:960 sc0"
        : "=&v"(h0),"=&v"(h1),"=&v"(h2),"=&v"(h3),"=&v"(h4),"=&v"(h5),"=&v"(h6),"=&v"(h7),
          "=&v"(h8),"=&v"(h9),"=&v"(h10),"=&v"(h11),"=&v"(h12),"=&v"(h13),"=&v"(h14),"=&v"(h15)
        : "v"(hb) : "memory");
      asm volatile("s_waitcnt vmcnt(0)" ::: "memory");
      __builtin_amdgcn_sched_barrier(0);
      hu[0]=__builtin_bit_cast(s16x8,h0);   hu[1]=__builtin_bit_cast(s16x8,h1);
      hu[2]=__builtin_bit_cast(s16x8,h2);   hu[3]=__builtin_bit_cast(s16x8,h3);
      hu[4]=__builtin_bit_cast(s16x8,h4);   hu[5]=__builtin_bit_cast(s16x8,h5);
      hu[6]=__builtin_bit_cast(s16x8,h6);   hu[7]=__builtin_bit_cast(s16x8,h7);
      hu[8]=__builtin_bit_cast(s16x8,h8);   hu[9]=__builtin_bit_cast(s16x8,h9);
      hu[10]=__builtin_bit_cast(s16x8,h10); hu[11]=__builtin_bit_cast(s16x8,h11);
      hu[12]=__builtin_bit_cast(s16x8,h12); hu[13]=__builtin_bit_cast(s16x8,h13);
      hu[14]=__builtin_bit_cast(s16x8,h14); hu[15]=__builtin_bit_cast(s16x8,h15);
    } else {
      const unsigned long long* hb =
          (const unsigned long long*)(hbuf + (size_t)(t & 1) * (NB * HID) + hoff);
#pragma unroll
      for (int ks = 0; ks < 16; ++ks) {
        union { unsigned long long q[2]; s16x8 s; } u;
        u.q[0] = __hip_atomic_load(hb + ks * 8,     __ATOMIC_RELAXED, __HIP_MEMORY_SCOPE_AGENT);
        u.q[1] = __hip_atomic_load(hb + ks * 8 + 1, __ATOMIC_RELAXED, __HIP_MEMORY_SCOPE_AGENT);
        hu[ks] = u.s;
      }
    }

    // ---- recurrent GEMM: hg = h[t] @ Whh^T ----
    f32x4 acc_b0 = {0.f, 0.f, 0.f, 0.f}, acc_b1 = {0.f, 0.f, 0.f, 0.f};
#pragma unroll
    for (int ks = 0; ks < 16; ks += 2) {
      acc_b0 = __builtin_amdgcn_mfma_f32_16x16x32_bf16(hu[ks],     wb[ks],     acc_b0, 0, 0, 0);
      acc_b1 = __builtin_amdgcn_mfma_f32_16x16x32_bf16(hu[ks + 1], wb[ks + 1], acc_b1, 0, 0, 0);
    }
    f32x4 acc_b = acc_b0 + acc_b1;

    // ---- exchange gate pre-activations across the 3 waves (dbuf LDS) ----
    float (*xc)[16][16] = xch[t & 1];
    if (g == 0)      { f32x4 s = acc_a + acc_b; *(f32x4*)&xc[0][ln][kg * 4] = s; }
    else if (g == 1) { f32x4 s = acc_a + acc_b; *(f32x4*)&xc[1][ln][kg * 4] = s; }
    else             { *(f32x4*)&xc[2][ln][kg * 4] = acc_a;
                       *(f32x4*)&xc[3][ln][kg * 4] = acc_b; }
    __syncthreads();
    f32x4 Sr  = *(const f32x4*)&xc[0][ln][kg * 4];
    f32x4 Sz  = *(const f32x4*)&xc[1][ln][kg * 4];
    f32x4 Snx = *(const f32x4*)&xc[2][ln][kg * 4];
    f32x4 Snh = *(const f32x4*)&xc[3][ln][kg * 4];

    // ---- gate math (all waves redundantly; keeps h_old in regs everywhere) ----
    float hnew[4];
#pragma unroll
    for (int i = 0; i < 4; ++i) {
      float r = 1.f / (1.f + __expf(-Sr[i]));
      float z = 1.f / (1.f + __expf(-Sz[i]));
      float pre = Snx[i] + r * (Snh[i] + bn);
      float e = __expf(2.f * pre);
      float n = 1.f - 2.f / (e + 1.f);   // tanh, overflow-safe
      hnew[i] = n + z * (hold[i] - n);
      hold[i] = hnew[i];
    }

    if (t == TLEN - 1) {
      if (g == 0) {
#pragma unroll
        for (int i = 0; i < 4; ++i)
          out[(size_t)(b0 + kg * 4 + i) * HID + u0 + ln] = hnew[i];
      }
    } else {
      // ---- publish h[t+1], drain, set flag = t+1; then x-GEMM t+1 ----
      if (g == 0) {
        unsigned short* hbn = hbuf + (size_t)((t + 1) & 1) * (NB * HID);
#pragma unroll
        for (int i = 0; i < 4; ++i) {
          int v  = (int)f2bf(hnew[i]);
          int o1 = __shfl_xor(v, 1);
          unsigned int p = (unsigned int)(v & 0xffff) | ((unsigned int)(o1 & 0xffff) << 16);
          unsigned int o2 = (unsigned int)__shfl_xor((int)p, 2);
          if ((ln & 3) == 0) {
            unsigned long long q = (unsigned long long)p | ((unsigned long long)o2 << 32);
            unsigned long long* qa =
                (unsigned long long*)(hbn + (size_t)(b0 + kg * 4 + i) * HID + u0 + ln);
            if (fast) *qa = q;                                   // plain -> L2
            else __hip_atomic_store(qa, q, __ATOMIC_RELAXED, __HIP_MEMORY_SCOPE_AGENT);
          }
        }
        asm volatile("s_waitcnt vmcnt(0)" ::: "memory");   // h stores at scope
        if (tid == 0) {
          unsigned* fw = &flags[bgrp * UGRPS + ugrp];
          if (fast) *(volatile unsigned*)fw = (unsigned)(t + 1);  // plain -> L2
          else __hip_atomic_store(fw, (unsigned)(t + 1),
                                  __ATOMIC_RELAXED, __HIP_MEMORY_SCOPE_AGENT);
        }
      }

      // ---- input-side GEMM for step t+1 (hides flag/data propagation) ----
      acc_a = (f32x4){bv, bv, bv, bv};
      const float* xp = xrow + (size_t)(t + 1) * INPUT;
#pragma unroll
      for (int ks = 0; ks < 16; ++ks) {
        s16x8 xa = cvt8(xp + ks * 32);
        acc_a = __builtin_amdgcn_mfma_f32_16x16x32_bf16(xa, wa[ks], acc_a, 0, 0, 0);
      }
    }
  }
}

extern "C" void kernel_launch(void* const* d_in, const int* in_sizes, int n_in,
                              void* d_out, int out_size, void* d_ws, size_t ws_size,
                              hipStream_t stream) {
  const float* xs     = (const float*)d_in[0];
  const float* wih    = (const float*)d_in[1];
  const float* whh    = (const float*)d_in[2];
  const float* bias   = (const float*)d_in[3];
  const float* bias_n = (const float*)d_in[4];
  float* out = (float*)d_out;

  const size_t hbuf_bytes = (size_t)2 * NB * HID * sizeof(unsigned short); // 256 KB
  const size_t flg_bytes  = (size_t)BGRPS * UGRPS * sizeof(unsigned int);  // 1 KB
  const size_t xcd_bytes  = (size_t)BGRPS * UGRPS * sizeof(unsigned int);  // 1 KB
  unsigned short* hbuf  = (unsigned short*)d_ws;
  unsigned int*   flags = (unsigned int*)((char*)d_ws + hbuf_bytes);
  unsigned int*   xcdm  = (unsigned int*)((char*)d_ws + hbuf_bytes + flg_bytes);

  hipMemsetAsync(d_ws, 0, hbuf_bytes + flg_bytes + xcd_bytes, stream);  // 258 KB

  gru_fused<<<dim3(BGRPS * UGRPS), dim3(192), 0, stream>>>(
      xs, wih, whh, bias, bias_n, out, hbuf, flags, xcdm);
}